// Round 2
// baseline (1085.370 us; speedup 1.0000x reference)
//
#include <hip/hip_runtime.h>

#define S_LEN 1024
#define HIDN  4096
#define NH    64
#define HD    64
#define NCH   32     // chunks
#define CLEN  32     // steps per chunk

typedef short bf16x8 __attribute__((ext_vector_type(8)));
typedef float f32x4  __attribute__((ext_vector_type(4)));

__device__ __forceinline__ unsigned short f2bf(float x){
  unsigned u = __float_as_uint(x);
  u += 0x7fffu + ((u >> 16) & 1u);   // round-to-nearest-even
  return (unsigned short)(u >> 16);
}

__device__ __forceinline__ void gload_lds16(const void* g, void* l){
  __builtin_amdgcn_global_load_lds(
      (const __attribute__((address_space(1))) void*)g,
      (__attribute__((address_space(3))) void*)l, 16, 0, 0);
}

// ------------- weight pre-convert: 5 x [4096][4096] fp32 -> bf16 -------------
__global__ __launch_bounds__(256)
void wconv_kernel(const float* __restrict__ w0, const float* __restrict__ w1,
                  const float* __restrict__ w2, const float* __restrict__ w3,
                  const float* __restrict__ w4, unsigned short* __restrict__ out)
{
  const int z = blockIdx.y;
  const float* __restrict__ w = (z==0)?w0:(z==1)?w1:(z==2)?w2:(z==3)?w3:w4;
  const size_t idx = (size_t)blockIdx.x * 2048 + (size_t)threadIdx.x * 8;
  float4 a = *(const float4*)(w + idx);
  float4 b = *(const float4*)(w + idx + 4);
  ushort4 lo, hi;
  lo.x = f2bf(a.x); lo.y = f2bf(a.y); lo.z = f2bf(a.z); lo.w = f2bf(a.w);
  hi.x = f2bf(b.x); hi.y = f2bf(b.y); hi.z = f2bf(b.z); hi.w = f2bf(b.w);
  unsigned short* o = out + (size_t)z * HIDN * HIDN + idx;
  *(ushort4*)(o)     = lo;
  *(ushort4*)(o + 4) = hi;
}

// ---------------- token-mix prepass: mixed[z][s][i] (bf16) -------------------
__global__ __launch_bounds__(256)
void mix_kernel(const float* __restrict__ hidden,
                const float* __restrict__ tmk, const float* __restrict__ tmv,
                const float* __restrict__ tmr, const float* __restrict__ tmg,
                unsigned short* __restrict__ mixed)
{
  int idx = blockIdx.x * 256 + threadIdx.x;      // 0 .. S*HID-1
  int i = idx & (HIDN - 1);
  float h  = hidden[idx];
  float sh = (idx >= HIDN) ? hidden[idx - HIDN] : 0.f;
  float mk = tmk[i], mv = tmv[i], mr = tmr[i], mg = tmg[i];
  mixed[idx + 0 * S_LEN * HIDN] = f2bf(h * mk + sh * (1.f - mk));
  mixed[idx + 1 * S_LEN * HIDN] = f2bf(h * mv + sh * (1.f - mv));
  mixed[idx + 2 * S_LEN * HIDN] = f2bf(h * mr + sh * (1.f - mr));
  mixed[idx + 3 * S_LEN * HIDN] = f2bf(h * mg + sh * (1.f - mg));
}

// --------- GEMM: C[z] = A[z](MxK bf16) @ W[z](NxK bf16)^T, m97-style ---------
// 128x128 tile, BK=32, 4 waves (2x2 of 64x64), 4x4 16x16x32 mfma frags/wave.
// global_load_lds width=16 staging for both A and B.
__global__ __launch_bounds__(256)
void gemm_lds(const unsigned short* __restrict__ Aall,
              const unsigned short* __restrict__ Wall,
              float* __restrict__ Call, int silu_mask)
{
  const int z = blockIdx.z;
  const unsigned short* __restrict__ A = Aall + (size_t)z * S_LEN * HIDN;
  const unsigned short* __restrict__ W = Wall + (size_t)z * HIDN * HIDN;
  float* __restrict__ C = Call + (size_t)z * S_LEN * HIDN;
  const int m0 = blockIdx.x * 128;
  const int n0 = blockIdx.y * 128;

  __shared__ unsigned short As[128 * 32];   // 8 KB
  __shared__ unsigned short Bs[128 * 32];   // 8 KB

  const int tid  = threadIdx.x;
  const int lane = tid & 63;
  const int wave = tid >> 6;
  const int wr = (wave >> 1) * 64;   // wave row offset in tile
  const int wc = (wave & 1) * 64;    // wave col offset in tile
  const int fr = lane & 15;          // fragment row (m) / col (n)
  const int fk = (lane >> 4) * 8;    // fragment k offset

  // staging coordinates: q in [0,512), 16B per q; row = q>>2, col8 = (q&3)*8
  const int q0 = tid, q1 = 256 + tid;
  const int r0 = q0 >> 2, c0 = (q0 & 3) * 8;
  const int r1 = q1 >> 2, c1 = (q1 & 3) * 8;
  const unsigned short* A0 = A + (size_t)(m0 + r0) * HIDN + c0;
  const unsigned short* A1 = A + (size_t)(m0 + r1) * HIDN + c1;
  const unsigned short* W0 = W + (size_t)(n0 + r0) * HIDN + c0;
  const unsigned short* W1 = W + (size_t)(n0 + r1) * HIDN + c1;

  f32x4 acc[4][4];
#pragma unroll
  for (int mi = 0; mi < 4; ++mi)
#pragma unroll
    for (int ni = 0; ni < 4; ++ni) acc[mi][ni] = (f32x4){0.f, 0.f, 0.f, 0.f};

  for (int k0 = 0; k0 < HIDN; k0 += 32) {
    gload_lds16(A0 + k0, &As[q0 * 8]);
    gload_lds16(A1 + k0, &As[q1 * 8]);
    gload_lds16(W0 + k0, &Bs[q0 * 8]);
    gload_lds16(W1 + k0, &Bs[q1 * 8]);
    __syncthreads();

    bf16x8 af[4], bq[4];
#pragma unroll
    for (int mi = 0; mi < 4; ++mi)
      af[mi] = *(const bf16x8*)(&As[(wr + mi * 16 + fr) * 32 + fk]);
#pragma unroll
    for (int ni = 0; ni < 4; ++ni)
      bq[ni] = *(const bf16x8*)(&Bs[(wc + ni * 16 + fr) * 32 + fk]);
#pragma unroll
    for (int mi = 0; mi < 4; ++mi)
#pragma unroll
      for (int ni = 0; ni < 4; ++ni)
        acc[mi][ni] = __builtin_amdgcn_mfma_f32_16x16x32_bf16(af[mi], bq[ni], acc[mi][ni], 0, 0, 0);
    __syncthreads();
  }

  const bool do_silu = (silu_mask >> z) & 1;
  const int orow = (lane >> 4) * 4;
#pragma unroll
  for (int mi = 0; mi < 4; ++mi)
#pragma unroll
    for (int ni = 0; ni < 4; ++ni)
#pragma unroll
      for (int r = 0; r < 4; ++r) {
        int row = m0 + wr + mi * 16 + orow + r;
        int col = n0 + wc + ni * 16 + fr;
        float v = acc[mi][ni][r];
        if (do_silu) v = v / (1.f + __expf(-v));
        C[(size_t)row * HIDN + col] = v;
      }
}

// -------------------- recurrence pass 1: local chunk states ------------------
// block (c,h), 64 lanes = e. st[d] in regs; k broadcast via shfl.
// X[c][h][d][e] = chunk-local final state (from zero initial).
__global__ __launch_bounds__(64)
void rec_pass1(const float* __restrict__ kb, const float* __restrict__ vb,
               const float* __restrict__ time_decay, float* __restrict__ X)
{
  const int c = blockIdx.x, h = blockIdx.y, e = threadIdx.x;
  const float tde = __expf(-__expf(time_decay[h * 64 + e]));
  float td[64];
#pragma unroll
  for (int d = 0; d < 64; ++d) td[d] = __shfl(tde, d, 64);
  float st[64];
#pragma unroll
  for (int d = 0; d < 64; ++d) st[d] = 0.f;

  for (int t = c * CLEN; t < c * CLEN + CLEN; ++t) {
    const size_t off = (size_t)t * HIDN + h * 64;
    const float kl = kb[off + e];
    const float vl = vb[off + e];
#pragma unroll
    for (int d = 0; d < 64; ++d)
      st[d] = fmaf(td[d], st[d], __shfl(kl, d, 64) * vl);
  }
#pragma unroll
  for (int d = 0; d < 64; ++d)
    X[(((size_t)c * NH + h) * 64 + d) * 64 + e] = st[d];
}

// ------------- recurrence pass 2: in-place scan of boundary states -----------
// After: X[c] = state ENTERING chunk c. td^CLEN = exp(-CLEN*exp(decay)).
__global__ __launch_bounds__(64)
void rec_pass2(const float* __restrict__ time_decay, float* __restrict__ X)
{
  const int h = blockIdx.x, e = threadIdx.x;
  const float tdce = __expf(-(float)CLEN * __expf(time_decay[h * 64 + e]));
  float tdc[64];
#pragma unroll
  for (int d = 0; d < 64; ++d) tdc[d] = __shfl(tdce, d, 64);
  float acc[64];
#pragma unroll
  for (int d = 0; d < 64; ++d) acc[d] = 0.f;
  for (int c = 0; c < NCH; ++c) {
#pragma unroll
    for (int d = 0; d < 64; ++d) {
      size_t idx = (((size_t)c * NH + h) * 64 + d) * 64 + e;
      float x = X[idx];
      X[idx] = acc[d];
      acc[d] = fmaf(tdc[d], acc[d], x);
    }
  }
}

// ------- recurrence pass 3: outputs + fused GroupNorm + gate -> A2 (bf16) ----
__global__ __launch_bounds__(64)
void rec_pass3(const float* __restrict__ kb, const float* __restrict__ vb,
               const float* __restrict__ rb, const float* __restrict__ gb,
               const float* __restrict__ time_decay, const float* __restrict__ time_faaaa,
               const float* __restrict__ gnw, const float* __restrict__ gnb,
               const float* __restrict__ X, unsigned short* __restrict__ A2)
{
  const int c = blockIdx.x, h = blockIdx.y, e = threadIdx.x;
  const float tde = __expf(-__expf(time_decay[h * 64 + e]));
  float td[64];
#pragma unroll
  for (int d = 0; d < 64; ++d) td[d] = __shfl(tde, d, 64);
  float st[64];
#pragma unroll
  for (int d = 0; d < 64; ++d)
    st[d] = X[(((size_t)c * NH + h) * 64 + d) * 64 + e];

  const float tf_l  = time_faaaa[h * 64 + e];
  const float gnw_l = gnw[h * 64 + e];
  const float gnb_l = gnb[h * 64 + e];

  for (int t = c * CLEN; t < c * CLEN + CLEN; ++t) {
    const size_t off = (size_t)t * HIDN + h * 64;
    const float kl = kb[off + e], rl = rb[off + e];
    const float vl = vb[off + e], gl = gb[off + e];

    // A = sum_d r[d]*tf[d]*k[d]; contributes A*v[e] to o.
    float Asum = rl * tf_l * kl;
#pragma unroll
    for (int i = 1; i < 64; i <<= 1) Asum += __shfl_xor(Asum, i, 64);

    float dot = 0.f;
#pragma unroll
    for (int d = 0; d < 64; ++d) {
      float kd = __shfl(kl, d, 64);
      float rd = __shfl(rl, d, 64);
      dot   = fmaf(rd, st[d], dot);                 // uses state_{t-1}
      st[d] = fmaf(td[d], st[d], kd * vl);          // state_t
    }
    float o = fmaf(Asum, vl, dot);

    // GroupNorm over the head (the 64 lanes of this wave)
    float s1 = o, s2 = o * o;
#pragma unroll
    for (int i = 1; i < 64; i <<= 1) {
      s1 += __shfl_xor(s1, i, 64);
      s2 += __shfl_xor(s2, i, 64);
    }
    float mean = s1 * (1.f / 64.f);
    float var  = s2 * (1.f / 64.f) - mean * mean;
    float xn   = (o - mean) * rsqrtf(var + 1e-5f);
    float yv   = xn * gnw_l + gnb_l;
    A2[off + e] = f2bf(gl * yv);
  }
}

// -----------------------------------------------------------------------------
extern "C" void kernel_launch(void* const* d_in, const int* in_sizes, int n_in,
                              void* d_out, int out_size, void* d_ws, size_t ws_size,
                              hipStream_t stream)
{
  const float* hidden     = (const float*)d_in[0];
  const float* w_key      = (const float*)d_in[1];
  const float* w_value    = (const float*)d_in[2];
  const float* w_recep    = (const float*)d_in[3];
  const float* w_gate     = (const float*)d_in[4];
  const float* w_output   = (const float*)d_in[5];
  const float* tmk        = (const float*)d_in[6];
  const float* tmv        = (const float*)d_in[7];
  const float* tmr        = (const float*)d_in[8];
  const float* tmg        = (const float*)d_in[9];
  const float* time_decay = (const float*)d_in[10];
  const float* time_faaaa = (const float*)d_in[11];
  const float* gnw        = (const float*)d_in[12];
  const float* gnb        = (const float*)d_in[13];
  float* out = (float*)d_out;

  char* ws = (char*)d_ws;
  // ws layout (bytes):
  //   wbf   bf16 [5][4096][4096]  @ 0          (167,772,160)  wk,wv,wr,wg,wo
  //   mixed bf16 [4][S][HID]      @ 167772160  (33,554,432)   (aliased by X after gemm4)
  //   kvrg  f32  [4][S][HID]      @ 201326592  (67,108,864)
  //   A2    bf16 [S][HID]         @ 268435456  (8,388,608)    total 276.8 MB
  unsigned short* wbf   = (unsigned short*)(ws);
  unsigned short* mixed = (unsigned short*)(ws + 167772160);
  float*          X     = (float*)(ws + 167772160);   // aliases mixed (dead after gemm4)
  float*          kvrg  = (float*)(ws + 201326592);
  unsigned short* A2    = (unsigned short*)(ws + 268435456);

  const float* kb = kvrg + 0 * (size_t)S_LEN * HIDN;
  const float* vb = kvrg + 1 * (size_t)S_LEN * HIDN;
  const float* rb = kvrg + 2 * (size_t)S_LEN * HIDN;
  const float* gb = kvrg + 3 * (size_t)S_LEN * HIDN;

  wconv_kernel<<<dim3(HIDN * HIDN / 2048, 5), 256, 0, stream>>>(
      w_key, w_value, w_recep, w_gate, w_output, wbf);

  mix_kernel<<<dim3(S_LEN * HIDN / 256), 256, 0, stream>>>(hidden, tmk, tmv, tmr, tmg, mixed);

  // k,v,r,g = mixed[z] @ W[z]^T ; silu on z==3 (gate)
  gemm_lds<<<dim3(8, 32, 4), 256, 0, stream>>>(mixed, wbf, kvrg, 0x8);

  rec_pass1<<<dim3(NCH, NH), 64, 0, stream>>>(kb, vb, time_decay, X);
  rec_pass2<<<dim3(NH), 64, 0, stream>>>(time_decay, X);
  rec_pass3<<<dim3(NCH, NH), 64, 0, stream>>>(kb, vb, rb, gb, time_decay, time_faaaa,
                                              gnw, gnb, X, A2);

  // out = (g * groupnorm(o)) @ w_output^T
  gemm_lds<<<dim3(8, 32, 1), 256, 0, stream>>>(A2, wbf + 4 * (size_t)HIDN * HIDN, out, 0x0);
}

// Round 3
// 869.139 us; speedup vs baseline: 1.2488x; 1.2488x over previous
//
#include <hip/hip_runtime.h>

#define S_LEN 1024
#define HIDN  4096
#define NH    64
#define HD    64
#define NCH   32     // chunks
#define CLEN  32     // steps per chunk

typedef short bf16x8 __attribute__((ext_vector_type(8)));
typedef float f32x4  __attribute__((ext_vector_type(4)));

__device__ __forceinline__ unsigned short f2bf(float x){
  unsigned u = __float_as_uint(x);
  u += 0x7fffu + ((u >> 16) & 1u);   // round-to-nearest-even
  return (unsigned short)(u >> 16);
}

__device__ __forceinline__ void gload_lds16(const void* g, void* l){
  __builtin_amdgcn_global_load_lds(
      (const __attribute__((address_space(1))) void*)g,
      (__attribute__((address_space(3))) void*)l, 16, 0, 0);
}

// ------------- weight pre-convert: 5 x [4096][4096] fp32 -> bf16 -------------
__global__ __launch_bounds__(256)
void wconv_kernel(const float* __restrict__ w0, const float* __restrict__ w1,
                  const float* __restrict__ w2, const float* __restrict__ w3,
                  const float* __restrict__ w4, unsigned short* __restrict__ out)
{
  const int z = blockIdx.y;
  const float* __restrict__ w = (z==0)?w0:(z==1)?w1:(z==2)?w2:(z==3)?w3:w4;
  const size_t idx = (size_t)blockIdx.x * 2048 + (size_t)threadIdx.x * 8;
  float4 a = *(const float4*)(w + idx);
  float4 b = *(const float4*)(w + idx + 4);
  ushort4 lo, hi;
  lo.x = f2bf(a.x); lo.y = f2bf(a.y); lo.z = f2bf(a.z); lo.w = f2bf(a.w);
  hi.x = f2bf(b.x); hi.y = f2bf(b.y); hi.z = f2bf(b.z); hi.w = f2bf(b.w);
  unsigned short* o = out + (size_t)z * HIDN * HIDN + idx;
  *(ushort4*)(o)     = lo;
  *(ushort4*)(o + 4) = hi;
}

// ---------------- token-mix prepass: mixed[z][s][i] (bf16) -------------------
__global__ __launch_bounds__(256)
void mix_kernel(const float* __restrict__ hidden,
                const float* __restrict__ tmk, const float* __restrict__ tmv,
                const float* __restrict__ tmr, const float* __restrict__ tmg,
                unsigned short* __restrict__ mixed)
{
  int idx = blockIdx.x * 256 + threadIdx.x;      // 0 .. S*HID-1
  int i = idx & (HIDN - 1);
  float h  = hidden[idx];
  float sh = (idx >= HIDN) ? hidden[idx - HIDN] : 0.f;
  float mk = tmk[i], mv = tmv[i], mr = tmr[i], mg = tmg[i];
  mixed[idx + 0 * S_LEN * HIDN] = f2bf(h * mk + sh * (1.f - mk));
  mixed[idx + 1 * S_LEN * HIDN] = f2bf(h * mv + sh * (1.f - mv));
  mixed[idx + 2 * S_LEN * HIDN] = f2bf(h * mr + sh * (1.f - mr));
  mixed[idx + 3 * S_LEN * HIDN] = f2bf(h * mg + sh * (1.f - mg));
}

// --------- GEMM: C[z] = A[z](MxK bf16) @ W[z](NxK bf16)^T, m97-style ---------
// 128x128 tile, BK=32, 4 waves (2x2 of 64x64), 4x4 16x16x32 mfma frags/wave.
// XCD-aware swizzle: linear grid; xcd = bid&7; all 8 m-tiles of an (n,z) strip
// land on the SAME xcd (bid%8 heuristic), so each xcd's L2 fetches each W-strip
// once instead of all 8 L2s fetching every strip. nzper = (Ntiles*Z)/8.
__global__ __launch_bounds__(256)
void gemm_lds(const unsigned short* __restrict__ Aall,
              const unsigned short* __restrict__ Wall,
              float* __restrict__ Call, int silu_mask, int nzper)
{
  const int bid  = blockIdx.x;
  const int xcd  = bid & 7;
  const int slot = bid >> 3;
  const int mt   = slot & 7;                 // 8 m-tiles (M=1024)
  const int nz   = xcd * nzper + (slot >> 3);
  const int nt   = nz & 31;                  // 32 n-tiles (N=4096)
  const int z    = nz >> 5;

  const unsigned short* __restrict__ A = Aall + (size_t)z * S_LEN * HIDN;
  const unsigned short* __restrict__ W = Wall + (size_t)z * HIDN * HIDN;
  float* __restrict__ C = Call + (size_t)z * S_LEN * HIDN;
  const int m0 = mt * 128;
  const int n0 = nt * 128;

  __shared__ unsigned short As[128 * 32];   // 8 KB
  __shared__ unsigned short Bs[128 * 32];   // 8 KB

  const int tid  = threadIdx.x;
  const int lane = tid & 63;
  const int wave = tid >> 6;
  const int wr = (wave >> 1) * 64;   // wave row offset in tile
  const int wc = (wave & 1) * 64;    // wave col offset in tile
  const int fr = lane & 15;          // fragment row (m) / col (n)
  const int fk = (lane >> 4) * 8;    // fragment k offset

  // staging coordinates: q in [0,512), 16B per q; row = q>>2, col8 = (q&3)*8
  const int q0 = tid, q1 = 256 + tid;
  const int r0 = q0 >> 2, c0 = (q0 & 3) * 8;
  const int r1 = q1 >> 2, c1 = (q1 & 3) * 8;
  const unsigned short* A0 = A + (size_t)(m0 + r0) * HIDN + c0;
  const unsigned short* A1 = A + (size_t)(m0 + r1) * HIDN + c1;
  const unsigned short* W0 = W + (size_t)(n0 + r0) * HIDN + c0;
  const unsigned short* W1 = W + (size_t)(n0 + r1) * HIDN + c1;

  f32x4 acc[4][4];
#pragma unroll
  for (int mi = 0; mi < 4; ++mi)
#pragma unroll
    for (int ni = 0; ni < 4; ++ni) acc[mi][ni] = (f32x4){0.f, 0.f, 0.f, 0.f};

  for (int k0 = 0; k0 < HIDN; k0 += 32) {
    gload_lds16(A0 + k0, &As[q0 * 8]);
    gload_lds16(A1 + k0, &As[q1 * 8]);
    gload_lds16(W0 + k0, &Bs[q0 * 8]);
    gload_lds16(W1 + k0, &Bs[q1 * 8]);
    __syncthreads();

    bf16x8 af[4], bq[4];
#pragma unroll
    for (int mi = 0; mi < 4; ++mi)
      af[mi] = *(const bf16x8*)(&As[(wr + mi * 16 + fr) * 32 + fk]);
#pragma unroll
    for (int ni = 0; ni < 4; ++ni)
      bq[ni] = *(const bf16x8*)(&Bs[(wc + ni * 16 + fr) * 32 + fk]);
#pragma unroll
    for (int mi = 0; mi < 4; ++mi)
#pragma unroll
      for (int ni = 0; ni < 4; ++ni)
        acc[mi][ni] = __builtin_amdgcn_mfma_f32_16x16x32_bf16(af[mi], bq[ni], acc[mi][ni], 0, 0, 0);
    __syncthreads();
  }

  const bool do_silu = (silu_mask >> z) & 1;
  const int orow = (lane >> 4) * 4;
#pragma unroll
  for (int mi = 0; mi < 4; ++mi)
#pragma unroll
    for (int ni = 0; ni < 4; ++ni)
#pragma unroll
      for (int r = 0; r < 4; ++r) {
        int row = m0 + wr + mi * 16 + orow + r;
        int col = n0 + wc + ni * 16 + fr;
        float v = acc[mi][ni][r];
        if (do_silu) v = v / (1.f + __expf(-v));
        C[(size_t)row * HIDN + col] = v;
      }
}

// -------------------- recurrence pass 1: local chunk states ------------------
// block (c,h), 64 lanes = e. st[d] in regs; k broadcast via shfl.
// X[c][h][d][e] = chunk-local final state (from zero initial).
__global__ __launch_bounds__(64)
void rec_pass1(const float* __restrict__ kb, const float* __restrict__ vb,
               const float* __restrict__ time_decay, float* __restrict__ X)
{
  const int c = blockIdx.x, h = blockIdx.y, e = threadIdx.x;
  const float tde = __expf(-__expf(time_decay[h * 64 + e]));
  float td[64];
#pragma unroll
  for (int d = 0; d < 64; ++d) td[d] = __shfl(tde, d, 64);
  float st[64];
#pragma unroll
  for (int d = 0; d < 64; ++d) st[d] = 0.f;

  for (int t = c * CLEN; t < c * CLEN + CLEN; ++t) {
    const size_t off = (size_t)t * HIDN + h * 64;
    const float kl = kb[off + e];
    const float vl = vb[off + e];
#pragma unroll
    for (int d = 0; d < 64; ++d)
      st[d] = fmaf(td[d], st[d], __shfl(kl, d, 64) * vl);
  }
#pragma unroll
  for (int d = 0; d < 64; ++d)
    X[(((size_t)c * NH + h) * 64 + d) * 64 + e] = st[d];
}

// ------------- recurrence pass 2: scan boundary states across chunks ---------
// Y[c] = state ENTERING chunk c (separate restrict buffer so loads pipeline —
// the round-2 in-place version serialized on vmcnt and cost ~200 us).
// grid (NH, 4): block handles 16 d's; lanes = e.
__global__ __launch_bounds__(64)
void rec_pass2(const float* __restrict__ time_decay,
               const float* __restrict__ X, float* __restrict__ Y)
{
  const int h = blockIdx.x, dq = blockIdx.y, e = threadIdx.x;
  float tdc[16];
#pragma unroll
  for (int i = 0; i < 16; ++i)
    tdc[i] = __expf(-(float)CLEN * __expf(time_decay[h * 64 + dq * 16 + i]));
  float acc[16];
#pragma unroll
  for (int i = 0; i < 16; ++i) acc[i] = 0.f;
  for (int c = 0; c < NCH; ++c) {
#pragma unroll
    for (int i = 0; i < 16; ++i) {
      size_t idx = (((size_t)c * NH + h) * 64 + dq * 16 + i) * 64 + e;
      Y[idx] = acc[i];
      acc[i] = fmaf(tdc[i], acc[i], X[idx]);
    }
  }
}

// ------- recurrence pass 3: outputs + fused GroupNorm + gate -> A2 (bf16) ----
__global__ __launch_bounds__(64)
void rec_pass3(const float* __restrict__ kb, const float* __restrict__ vb,
               const float* __restrict__ rb, const float* __restrict__ gb,
               const float* __restrict__ time_decay, const float* __restrict__ time_faaaa,
               const float* __restrict__ gnw, const float* __restrict__ gnb,
               const float* __restrict__ Y, unsigned short* __restrict__ A2)
{
  const int c = blockIdx.x, h = blockIdx.y, e = threadIdx.x;
  const float tde = __expf(-__expf(time_decay[h * 64 + e]));
  float td[64];
#pragma unroll
  for (int d = 0; d < 64; ++d) td[d] = __shfl(tde, d, 64);
  float st[64];
#pragma unroll
  for (int d = 0; d < 64; ++d)
    st[d] = Y[(((size_t)c * NH + h) * 64 + d) * 64 + e];

  const float tf_l  = time_faaaa[h * 64 + e];
  const float gnw_l = gnw[h * 64 + e];
  const float gnb_l = gnb[h * 64 + e];

  for (int t = c * CLEN; t < c * CLEN + CLEN; ++t) {
    const size_t off = (size_t)t * HIDN + h * 64;
    const float kl = kb[off + e], rl = rb[off + e];
    const float vl = vb[off + e], gl = gb[off + e];

    // A = sum_d r[d]*tf[d]*k[d]; contributes A*v[e] to o.
    float Asum = rl * tf_l * kl;
#pragma unroll
    for (int i = 1; i < 64; i <<= 1) Asum += __shfl_xor(Asum, i, 64);

    float dot = 0.f;
#pragma unroll
    for (int d = 0; d < 64; ++d) {
      float kd = __shfl(kl, d, 64);
      float rd = __shfl(rl, d, 64);
      dot   = fmaf(rd, st[d], dot);                 // uses state_{t-1}
      st[d] = fmaf(td[d], st[d], kd * vl);          // state_t
    }
    float o = fmaf(Asum, vl, dot);

    // GroupNorm over the head (the 64 lanes of this wave)
    float s1 = o, s2 = o * o;
#pragma unroll
    for (int i = 1; i < 64; i <<= 1) {
      s1 += __shfl_xor(s1, i, 64);
      s2 += __shfl_xor(s2, i, 64);
    }
    float mean = s1 * (1.f / 64.f);
    float var  = s2 * (1.f / 64.f) - mean * mean;
    float xn   = (o - mean) * rsqrtf(var + 1e-5f);
    float yv   = xn * gnw_l + gnb_l;
    A2[off + e] = f2bf(gl * yv);
  }
}

// -----------------------------------------------------------------------------
extern "C" void kernel_launch(void* const* d_in, const int* in_sizes, int n_in,
                              void* d_out, int out_size, void* d_ws, size_t ws_size,
                              hipStream_t stream)
{
  const float* hidden     = (const float*)d_in[0];
  const float* w_key      = (const float*)d_in[1];
  const float* w_value    = (const float*)d_in[2];
  const float* w_recep    = (const float*)d_in[3];
  const float* w_gate     = (const float*)d_in[4];
  const float* w_output   = (const float*)d_in[5];
  const float* tmk        = (const float*)d_in[6];
  const float* tmv        = (const float*)d_in[7];
  const float* tmr        = (const float*)d_in[8];
  const float* tmg        = (const float*)d_in[9];
  const float* time_decay = (const float*)d_in[10];
  const float* time_faaaa = (const float*)d_in[11];
  const float* gnw        = (const float*)d_in[12];
  const float* gnb        = (const float*)d_in[13];
  float* out = (float*)d_out;

  char* ws = (char*)d_ws;
  // ws layout (bytes):
  //   wbf   bf16 [5][4096][4096]  @ 0          (167,772,160)  wk,wv,wr,wg,wo
  //     Y   f32  [32][64][64][64] @ 0          (33,554,432)   aliases wk+wv
  //                                             (dead after gemm4; wo @134MB untouched)
  //   mixed bf16 [4][S][HID]      @ 167772160  (33,554,432)   (aliased by X after gemm4)
  //   kvrg  f32  [4][S][HID]      @ 201326592  (67,108,864)
  //   A2    bf16 [S][HID]         @ 268435456  (8,388,608)    total 276.8 MB
  unsigned short* wbf   = (unsigned short*)(ws);
  float*          Y     = (float*)(ws);               // aliases wk/wv (dead after gemm4)
  unsigned short* mixed = (unsigned short*)(ws + 167772160);
  float*          X     = (float*)(ws + 167772160);   // aliases mixed (dead after gemm4)
  float*          kvrg  = (float*)(ws + 201326592);
  unsigned short* A2    = (unsigned short*)(ws + 268435456);

  const float* kb = kvrg + 0 * (size_t)S_LEN * HIDN;
  const float* vb = kvrg + 1 * (size_t)S_LEN * HIDN;
  const float* rb = kvrg + 2 * (size_t)S_LEN * HIDN;
  const float* gb = kvrg + 3 * (size_t)S_LEN * HIDN;

  wconv_kernel<<<dim3(HIDN * HIDN / 2048, 5), 256, 0, stream>>>(
      w_key, w_value, w_recep, w_gate, w_output, wbf);

  mix_kernel<<<dim3(S_LEN * HIDN / 256), 256, 0, stream>>>(hidden, tmk, tmv, tmr, tmg, mixed);

  // k,v,r,g = mixed[z] @ W[z]^T ; silu on z==3 (gate). 1024 blocks, nzper=128/8.
  gemm_lds<<<dim3(1024), 256, 0, stream>>>(mixed, wbf, kvrg, 0x8, 16);

  rec_pass1<<<dim3(NCH, NH), 64, 0, stream>>>(kb, vb, time_decay, X);
  rec_pass2<<<dim3(NH, 4), 64, 0, stream>>>(time_decay, X, Y);
  rec_pass3<<<dim3(NCH, NH), 64, 0, stream>>>(kb, vb, rb, gb, time_decay, time_faaaa,
                                              gnw, gnb, Y, A2);

  // out = (g * groupnorm(o)) @ w_output^T. 256 blocks, nzper=32/8.
  gemm_lds<<<dim3(256), 256, 0, stream>>>(A2, wbf + 4 * (size_t)HIDN * HIDN, out, 0x0, 4);
}

// Round 4
// 709.176 us; speedup vs baseline: 1.5305x; 1.2256x over previous
//
#include <hip/hip_runtime.h>

#define S_LEN 1024
#define HIDN  4096
#define NH    64
#define HD    64
#define NCH   32     // chunks
#define CLEN  32     // steps per chunk

typedef short bf16x8 __attribute__((ext_vector_type(8)));
typedef float f32x4  __attribute__((ext_vector_type(4)));

__device__ __forceinline__ unsigned short f2bf(float x){
  unsigned u = __float_as_uint(x);
  u += 0x7fffu + ((u >> 16) & 1u);   // round-to-nearest-even
  return (unsigned short)(u >> 16);
}

__device__ __forceinline__ void gload_lds16(const void* g, void* l){
  __builtin_amdgcn_global_load_lds(
      (const __attribute__((address_space(1))) void*)g,
      (__attribute__((address_space(3))) void*)l, 16, 0, 0);
}

// ------------- weight pre-convert: 5 x [4096][4096] fp32 -> bf16 -------------
__global__ __launch_bounds__(256)
void wconv_kernel(const float* __restrict__ w0, const float* __restrict__ w1,
                  const float* __restrict__ w2, const float* __restrict__ w3,
                  const float* __restrict__ w4, unsigned short* __restrict__ out)
{
  const int z = blockIdx.y;
  const float* __restrict__ w = (z==0)?w0:(z==1)?w1:(z==2)?w2:(z==3)?w3:w4;
  const size_t idx = (size_t)blockIdx.x * 2048 + (size_t)threadIdx.x * 8;
  float4 a = *(const float4*)(w + idx);
  float4 b = *(const float4*)(w + idx + 4);
  ushort4 lo, hi;
  lo.x = f2bf(a.x); lo.y = f2bf(a.y); lo.z = f2bf(a.z); lo.w = f2bf(a.w);
  hi.x = f2bf(b.x); hi.y = f2bf(b.y); hi.z = f2bf(b.z); hi.w = f2bf(b.w);
  unsigned short* o = out + (size_t)z * HIDN * HIDN + idx;
  *(ushort4*)(o)     = lo;
  *(ushort4*)(o + 4) = hi;
}

// ---------------- token-mix prepass: mixed[z][s][i] (bf16) -------------------
__global__ __launch_bounds__(256)
void mix_kernel(const float* __restrict__ hidden,
                const float* __restrict__ tmk, const float* __restrict__ tmv,
                const float* __restrict__ tmr, const float* __restrict__ tmg,
                unsigned short* __restrict__ mixed)
{
  int idx = blockIdx.x * 256 + threadIdx.x;      // 0 .. S*HID-1
  int i = idx & (HIDN - 1);
  float h  = hidden[idx];
  float sh = (idx >= HIDN) ? hidden[idx - HIDN] : 0.f;
  float mk = tmk[i], mv = tmv[i], mr = tmr[i], mg = tmg[i];
  mixed[idx + 0 * S_LEN * HIDN] = f2bf(h * mk + sh * (1.f - mk));
  mixed[idx + 1 * S_LEN * HIDN] = f2bf(h * mv + sh * (1.f - mv));
  mixed[idx + 2 * S_LEN * HIDN] = f2bf(h * mr + sh * (1.f - mr));
  mixed[idx + 3 * S_LEN * HIDN] = f2bf(h * mg + sh * (1.f - mg));
}

// --------- GEMM: C[z] = A[z](MxK bf16) @ W[z](NxK bf16)^T --------------------
// 128x128 tile, BK=64 as TWO BK=32 sub-tiles per barrier window (halves the
// vmcnt(0)+s_barrier drains vs BK=32; sub-tiles keep the 64B row stride so the
// 2-way-free LDS bank behavior and the wave-uniform global_load_lds layout are
// preserved — padding is illegal with lds-DMA).
// XCD swizzle: xcd=bid&7; all 8 m-tiles of an (n,z) strip on one XCD.
__global__ __launch_bounds__(256)
void gemm_lds(const unsigned short* __restrict__ Aall,
              const unsigned short* __restrict__ Wall,
              float* __restrict__ Call, int silu_mask, int nzper)
{
  const int bid  = blockIdx.x;
  const int xcd  = bid & 7;
  const int slot = bid >> 3;
  const int mt   = slot & 7;                 // 8 m-tiles (M=1024)
  const int nz   = xcd * nzper + (slot >> 3);
  const int nt   = nz & 31;                  // 32 n-tiles (N=4096)
  const int z    = nz >> 5;

  const unsigned short* __restrict__ A = Aall + (size_t)z * S_LEN * HIDN;
  const unsigned short* __restrict__ W = Wall + (size_t)z * HIDN * HIDN;
  float* __restrict__ C = Call + (size_t)z * S_LEN * HIDN;
  const int m0 = mt * 128;
  const int n0 = nt * 128;

  __shared__ unsigned short As[2][128 * 32];   // 2 x 8 KB
  __shared__ unsigned short Bs[2][128 * 32];   // 2 x 8 KB

  const int tid  = threadIdx.x;
  const int lane = tid & 63;
  const int wave = tid >> 6;
  const int wr = (wave >> 1) * 64;
  const int wc = (wave & 1) * 64;
  const int fr = lane & 15;
  const int fk = (lane >> 4) * 8;

  // staging: q in [0,512), 16B per q; row = q>>2, col8 = (q&3)*8
  const int q0 = tid, q1 = 256 + tid;
  const int r0 = q0 >> 2, c0 = (q0 & 3) * 8;
  const int r1 = q1 >> 2, c1 = (q1 & 3) * 8;
  const unsigned short* A0 = A + (size_t)(m0 + r0) * HIDN + c0;
  const unsigned short* A1 = A + (size_t)(m0 + r1) * HIDN + c1;
  const unsigned short* W0 = W + (size_t)(n0 + r0) * HIDN + c0;
  const unsigned short* W1 = W + (size_t)(n0 + r1) * HIDN + c1;

  f32x4 acc[4][4];
#pragma unroll
  for (int mi = 0; mi < 4; ++mi)
#pragma unroll
    for (int ni = 0; ni < 4; ++ni) acc[mi][ni] = (f32x4){0.f, 0.f, 0.f, 0.f};

  for (int k0 = 0; k0 < HIDN; k0 += 64) {
    gload_lds16(A0 + k0,      &As[0][q0 * 8]);
    gload_lds16(A1 + k0,      &As[0][q1 * 8]);
    gload_lds16(A0 + k0 + 32, &As[1][q0 * 8]);
    gload_lds16(A1 + k0 + 32, &As[1][q1 * 8]);
    gload_lds16(W0 + k0,      &Bs[0][q0 * 8]);
    gload_lds16(W1 + k0,      &Bs[0][q1 * 8]);
    gload_lds16(W0 + k0 + 32, &Bs[1][q0 * 8]);
    gload_lds16(W1 + k0 + 32, &Bs[1][q1 * 8]);
    __syncthreads();

#pragma unroll
    for (int kk = 0; kk < 2; ++kk) {
      bf16x8 af[4], bq[4];
#pragma unroll
      for (int mi = 0; mi < 4; ++mi)
        af[mi] = *(const bf16x8*)(&As[kk][(wr + mi * 16 + fr) * 32 + fk]);
#pragma unroll
      for (int ni = 0; ni < 4; ++ni)
        bq[ni] = *(const bf16x8*)(&Bs[kk][(wc + ni * 16 + fr) * 32 + fk]);
#pragma unroll
      for (int mi = 0; mi < 4; ++mi)
#pragma unroll
        for (int ni = 0; ni < 4; ++ni)
          acc[mi][ni] = __builtin_amdgcn_mfma_f32_16x16x32_bf16(af[mi], bq[ni], acc[mi][ni], 0, 0, 0);
    }
    __syncthreads();
  }

  const bool do_silu = (silu_mask >> z) & 1;
  const int orow = (lane >> 4) * 4;
#pragma unroll
  for (int mi = 0; mi < 4; ++mi)
#pragma unroll
    for (int ni = 0; ni < 4; ++ni)
#pragma unroll
      for (int r = 0; r < 4; ++r) {
        int row = m0 + wr + mi * 16 + orow + r;
        int col = n0 + wc + ni * 16 + fr;
        float v = acc[mi][ni][r];
        if (do_silu) v = v / (1.f + __expf(-v));
        C[(size_t)row * HIDN + col] = v;
      }
}

// --------- split-K GEMM for the final projection: C += A @ W^T ---------------
// 512 blocks (2 k-splits) -> 2 blocks/CU instead of 1. fp32 atomicAdd epilogue
// (exactly 2 writers/address, no contention). C must be zeroed first.
__global__ __launch_bounds__(256)
void gemm_splitk(const unsigned short* __restrict__ A,
                 const unsigned short* __restrict__ W,
                 float* __restrict__ C)
{
  const int bid  = blockIdx.x;
  const int xcd  = bid & 7;
  const int slot = bid >> 3;                 // 0..63
  const int mt   = slot & 7;
  const int nl   = (slot >> 3) & 3;
  const int ks   = slot >> 5;                // 0..1
  const int nt   = xcd * 4 + nl;
  const int m0 = mt * 128, n0 = nt * 128;
  const int kb = ks * (HIDN / 2), ke = kb + (HIDN / 2);

  __shared__ unsigned short As[2][128 * 32];
  __shared__ unsigned short Bs[2][128 * 32];

  const int tid  = threadIdx.x;
  const int lane = tid & 63;
  const int wave = tid >> 6;
  const int wr = (wave >> 1) * 64;
  const int wc = (wave & 1) * 64;
  const int fr = lane & 15;
  const int fk = (lane >> 4) * 8;

  const int q0 = tid, q1 = 256 + tid;
  const int r0 = q0 >> 2, c0 = (q0 & 3) * 8;
  const int r1 = q1 >> 2, c1 = (q1 & 3) * 8;
  const unsigned short* A0 = A + (size_t)(m0 + r0) * HIDN + c0;
  const unsigned short* A1 = A + (size_t)(m0 + r1) * HIDN + c1;
  const unsigned short* W0 = W + (size_t)(n0 + r0) * HIDN + c0;
  const unsigned short* W1 = W + (size_t)(n0 + r1) * HIDN + c1;

  f32x4 acc[4][4];
#pragma unroll
  for (int mi = 0; mi < 4; ++mi)
#pragma unroll
    for (int ni = 0; ni < 4; ++ni) acc[mi][ni] = (f32x4){0.f, 0.f, 0.f, 0.f};

  for (int k0 = kb; k0 < ke; k0 += 64) {
    gload_lds16(A0 + k0,      &As[0][q0 * 8]);
    gload_lds16(A1 + k0,      &As[0][q1 * 8]);
    gload_lds16(A0 + k0 + 32, &As[1][q0 * 8]);
    gload_lds16(A1 + k0 + 32, &As[1][q1 * 8]);
    gload_lds16(W0 + k0,      &Bs[0][q0 * 8]);
    gload_lds16(W1 + k0,      &Bs[0][q1 * 8]);
    gload_lds16(W0 + k0 + 32, &Bs[1][q0 * 8]);
    gload_lds16(W1 + k0 + 32, &Bs[1][q1 * 8]);
    __syncthreads();

#pragma unroll
    for (int kk = 0; kk < 2; ++kk) {
      bf16x8 af[4], bq[4];
#pragma unroll
      for (int mi = 0; mi < 4; ++mi)
        af[mi] = *(const bf16x8*)(&As[kk][(wr + mi * 16 + fr) * 32 + fk]);
#pragma unroll
      for (int ni = 0; ni < 4; ++ni)
        bq[ni] = *(const bf16x8*)(&Bs[kk][(wc + ni * 16 + fr) * 32 + fk]);
#pragma unroll
      for (int mi = 0; mi < 4; ++mi)
#pragma unroll
        for (int ni = 0; ni < 4; ++ni)
          acc[mi][ni] = __builtin_amdgcn_mfma_f32_16x16x32_bf16(af[mi], bq[ni], acc[mi][ni], 0, 0, 0);
    }
    __syncthreads();
  }

  const int orow = (lane >> 4) * 4;
#pragma unroll
  for (int mi = 0; mi < 4; ++mi)
#pragma unroll
    for (int ni = 0; ni < 4; ++ni)
#pragma unroll
      for (int r = 0; r < 4; ++r) {
        int row = m0 + wr + mi * 16 + orow + r;
        int col = n0 + wc + ni * 16 + fr;
        atomicAdd(&C[(size_t)row * HIDN + col], acc[mi][ni][r]);
      }
}

// -------------------- recurrence pass 1: local chunk states ------------------
// block (c,h), 64 lanes = e. st[d] in regs. k[d] fetched via WAVE-UNIFORM
// loads (krow[d], d unrolled-const) -> compiler scalarizes to s_load: keeps
// the inner loop off the per-CU-serialized LDS pipe (shfl = ds_bpermute).
__global__ __launch_bounds__(64)
void rec_pass1(const float* __restrict__ kb, const float* __restrict__ vb,
               const float* __restrict__ time_decay, float* __restrict__ X)
{
  const int c = blockIdx.x, h = blockIdx.y, e = threadIdx.x;
  const float tde = __expf(-__expf(time_decay[h * 64 + e]));
  float td[64];
#pragma unroll
  for (int d = 0; d < 64; ++d) td[d] = __shfl(tde, d, 64);
  float st[64];
#pragma unroll
  for (int d = 0; d < 64; ++d) st[d] = 0.f;

  for (int t = c * CLEN; t < c * CLEN + CLEN; ++t) {
    const size_t off = (size_t)t * HIDN + h * 64;
    const float vl = vb[off + e];
    const float* __restrict__ krow = kb + off;   // uniform address over d
#pragma unroll
    for (int d = 0; d < 64; ++d)
      st[d] = fmaf(td[d], st[d], krow[d] * vl);
  }
#pragma unroll
  for (int d = 0; d < 64; ++d)
    X[(((size_t)c * NH + h) * 64 + d) * 64 + e] = st[d];
}

// ------------- recurrence pass 2: scan boundary states across chunks ---------
// Y[c] = state ENTERING chunk c (separate restrict buffer so loads pipeline —
// in-place RMW version serialized on vmcnt and cost ~200 us).
__global__ __launch_bounds__(64)
void rec_pass2(const float* __restrict__ time_decay,
               const float* __restrict__ X, float* __restrict__ Y)
{
  const int h = blockIdx.x, dq = blockIdx.y, e = threadIdx.x;
  float tdc[16];
#pragma unroll
  for (int i = 0; i < 16; ++i)
    tdc[i] = __expf(-(float)CLEN * __expf(time_decay[h * 64 + dq * 16 + i]));
  float acc[16];
#pragma unroll
  for (int i = 0; i < 16; ++i) acc[i] = 0.f;
  for (int c = 0; c < NCH; ++c) {
#pragma unroll
    for (int i = 0; i < 16; ++i) {
      size_t idx = (((size_t)c * NH + h) * 64 + dq * 16 + i) * 64 + e;
      Y[idx] = acc[i];
      acc[i] = fmaf(tdc[i], acc[i], X[idx]);
    }
  }
}

// ------- recurrence pass 3: outputs + fused GroupNorm + gate -> A2 (bf16) ----
__global__ __launch_bounds__(64)
void rec_pass3(const float* __restrict__ kb, const float* __restrict__ vb,
               const float* __restrict__ rb, const float* __restrict__ gb,
               const float* __restrict__ time_decay, const float* __restrict__ time_faaaa,
               const float* __restrict__ gnw, const float* __restrict__ gnb,
               const float* __restrict__ Y, unsigned short* __restrict__ A2)
{
  const int c = blockIdx.x, h = blockIdx.y, e = threadIdx.x;
  const float tde = __expf(-__expf(time_decay[h * 64 + e]));
  float td[64];
#pragma unroll
  for (int d = 0; d < 64; ++d) td[d] = __shfl(tde, d, 64);
  float st[64];
#pragma unroll
  for (int d = 0; d < 64; ++d)
    st[d] = Y[(((size_t)c * NH + h) * 64 + d) * 64 + e];

  const float tf_l  = time_faaaa[h * 64 + e];
  const float gnw_l = gnw[h * 64 + e];
  const float gnb_l = gnb[h * 64 + e];

  for (int t = c * CLEN; t < c * CLEN + CLEN; ++t) {
    const size_t off = (size_t)t * HIDN + h * 64;
    const float kl = kb[off + e], rl = rb[off + e];
    const float vl = vb[off + e], gl = gb[off + e];

    // A = sum_d r[d]*tf[d]*k[d]; contributes A*v[e] to o.
    float Asum = rl * tf_l * kl;
#pragma unroll
    for (int i = 1; i < 64; i <<= 1) Asum += __shfl_xor(Asum, i, 64);

    const float* __restrict__ krow = kb + off;   // uniform address over d
    const float* __restrict__ rrow = rb + off;
    float dot = 0.f;
#pragma unroll
    for (int d = 0; d < 64; ++d) {
      dot   = fmaf(rrow[d], st[d], dot);                 // uses state_{t-1}
      st[d] = fmaf(td[d], st[d], krow[d] * vl);          // state_t
    }
    float o = fmaf(Asum, vl, dot);

    // GroupNorm over the head (the 64 lanes of this wave)
    float s1 = o, s2 = o * o;
#pragma unroll
    for (int i = 1; i < 64; i <<= 1) {
      s1 += __shfl_xor(s1, i, 64);
      s2 += __shfl_xor(s2, i, 64);
    }
    float mean = s1 * (1.f / 64.f);
    float var  = s2 * (1.f / 64.f) - mean * mean;
    float xn   = (o - mean) * rsqrtf(var + 1e-5f);
    float yv   = xn * gnw_l + gnb_l;
    A2[off + e] = f2bf(gl * yv);
  }
}

// -----------------------------------------------------------------------------
extern "C" void kernel_launch(void* const* d_in, const int* in_sizes, int n_in,
                              void* d_out, int out_size, void* d_ws, size_t ws_size,
                              hipStream_t stream)
{
  const float* hidden     = (const float*)d_in[0];
  const float* w_key      = (const float*)d_in[1];
  const float* w_value    = (const float*)d_in[2];
  const float* w_recep    = (const float*)d_in[3];
  const float* w_gate     = (const float*)d_in[4];
  const float* w_output   = (const float*)d_in[5];
  const float* tmk        = (const float*)d_in[6];
  const float* tmv        = (const float*)d_in[7];
  const float* tmr        = (const float*)d_in[8];
  const float* tmg        = (const float*)d_in[9];
  const float* time_decay = (const float*)d_in[10];
  const float* time_faaaa = (const float*)d_in[11];
  const float* gnw        = (const float*)d_in[12];
  const float* gnb        = (const float*)d_in[13];
  float* out = (float*)d_out;

  char* ws = (char*)d_ws;
  // ws layout (bytes):
  //   wbf   bf16 [5][4096][4096]  @ 0          (167,772,160)  wk,wv,wr,wg,wo
  //     Y   f32  [32][64][64][64] @ 0          (33,554,432)   aliases wk+wv (dead after gemm4)
  //   mixed bf16 [4][S][HID]      @ 167772160  (33,554,432)
  //     X   f32  [32][64][64][64] @ 167772160  aliases mixed  (dead after gemm4)
  //   kvrg  f32  [4][S][HID]      @ 201326592  (67,108,864)
  //   A2    bf16 [S][HID]         @ 268435456  (8,388,608)    total 276.8 MB
  unsigned short* wbf   = (unsigned short*)(ws);
  float*          Y     = (float*)(ws);
  unsigned short* mixed = (unsigned short*)(ws + 167772160);
  float*          X     = (float*)(ws + 167772160);
  float*          kvrg  = (float*)(ws + 201326592);
  unsigned short* A2    = (unsigned short*)(ws + 268435456);

  const float* kb = kvrg + 0 * (size_t)S_LEN * HIDN;
  const float* vb = kvrg + 1 * (size_t)S_LEN * HIDN;
  const float* rb = kvrg + 2 * (size_t)S_LEN * HIDN;
  const float* gb = kvrg + 3 * (size_t)S_LEN * HIDN;

  wconv_kernel<<<dim3(HIDN * HIDN / 2048, 5), 256, 0, stream>>>(
      w_key, w_value, w_recep, w_gate, w_output, wbf);

  mix_kernel<<<dim3(S_LEN * HIDN / 256), 256, 0, stream>>>(hidden, tmk, tmv, tmr, tmg, mixed);

  // k,v,r,g = mixed[z] @ W[z]^T ; silu on z==3 (gate). 1024 blocks, nzper=128/8.
  gemm_lds<<<dim3(1024), 256, 0, stream>>>(mixed, wbf, kvrg, 0x8, 16);

  rec_pass1<<<dim3(NCH, NH), 64, 0, stream>>>(kb, vb, time_decay, X);
  rec_pass2<<<dim3(NH, 4), 64, 0, stream>>>(time_decay, X, Y);
  rec_pass3<<<dim3(NCH, NH), 64, 0, stream>>>(kb, vb, rb, gb, time_decay, time_faaaa,
                                              gnw, gnb, Y, A2);

  // out = (g * groupnorm(o)) @ w_output^T, split-K x2 with atomic epilogue.
  hipMemsetAsync(d_out, 0, (size_t)out_size * sizeof(float), stream);
  gemm_splitk<<<dim3(512), 256, 0, stream>>>(A2, wbf + 4 * (size_t)HIDN * HIDN, out);
}